// Round 13
// baseline (5055.866 us; speedup 1.0000x reference)
//
#include <hip/hip_runtime.h>

using short8 = __attribute__((ext_vector_type(8))) short;
using f32x4  = __attribute__((ext_vector_type(4))) float;

typedef unsigned short u16;
typedef unsigned int   u32;
typedef unsigned long long u64;

#define T_SEQ 256
#define BATCH 64
#define INP   256
#define HID   1024
#define GDIM  4096
#define KC    1280   // HID + INP
#define OUTD  1024

#define NSL   40     // K slices of 32 (32 h + 8 x)
#define NBLK  512    // 256 per direction, 4 h-cols each
#define DBLK  256    // blocks per direction
#define LDSB  (NSL * 64 * 8 * 2)   // 40960 bytes dynamic LDS (16 gate-cols)

#define MFMA16(a,b,c) __builtin_amdgcn_mfma_f32_16x16x32_bf16(a,b,c,0,0,0)

__device__ __forceinline__ u16 f2bf(float f){
  union { float f; u32 u; } v; v.f = f;
  u32 r = v.u + 0x7fffu + ((v.u >> 16) & 1u);
  return (u16)(r >> 16);
}
__device__ __forceinline__ float sigm(float x){ return 1.f/(1.f+__expf(-x)); }
__device__ __forceinline__ float tanhf_(float x){ return 1.f - 2.f/(__expf(2.f*x)+1.f); }

// agent-scope (device-coherent, IC-resident) ops — compiler emits sc1
__device__ __forceinline__ void ag_st_u32(u32* p, u32 v){
  __hip_atomic_store(p, v, __ATOMIC_RELAXED, __HIP_MEMORY_SCOPE_AGENT);
}
__device__ __forceinline__ u64 ag_ld_u64(const u64* p){
  return __hip_atomic_load(p, __ATOMIC_RELAXED, __HIP_MEMORY_SCOPE_AGENT);
}

// quad-perm DPP: 4 gates of one h-col live in one lane-quad
template<int CTRL>
__device__ __forceinline__ float qperm(float v){
  union { float f; int i; } u; u.f = v;
  u.i = __builtin_amdgcn_mov_dpp(u.i, CTRL, 0xf, 0xf, true);
  return u.f;
}
#define QP_XOR1 177   // quad_perm [1,0,3,2]
#define QP_XOR2 78    // quad_perm [2,3,0,1]

// ---------------------------------------------------------------------------
// Prep: combined recurrent weights, bf16.
// Block nb (0..255/dir) owns gate-cols [nb*16, nb*16+16):
//   n = (j>>2)*16 + (j&3)*4 + gate   (h-col j; one lane-quad = 4 gates of j)
// Rows k<1024 -> Wh[k][gate*1024+j], k>=1024 -> Wx[k-1024][gate*1024+j].
// ---------------------------------------------------------------------------
__global__ void build_wc(const float* __restrict__ WhF, const float* __restrict__ WxF,
                         const float* __restrict__ WhB, const float* __restrict__ WxB,
                         u16* __restrict__ WcF, u16* __restrict__ WcB)
{
  const int z = blockIdx.z; const int dir = z >> 2, gate = z & 3;
  const float* Wh = dir ? WhB : WhF;
  const float* Wx = dir ? WxB : WxF;
  u16* Wc = dir ? WcB : WcF;
  const int k0 = blockIdx.x * 64, j0 = blockIdx.y * 64;
  __shared__ float tile[64][65];
  const int t = threadIdx.x;
  #pragma unroll
  for (int i = 0; i < 16; ++i) {
    int idx = i*256 + t; int kr = idx >> 6, jc = idx & 63;
    int k = k0 + kr;
    float v = (k < HID) ? Wh[(size_t)k*GDIM + gate*HID + j0 + jc]
                        : Wx[(size_t)(k-HID)*GDIM + gate*HID + j0 + jc];
    tile[kr][jc] = v;
  }
  __syncthreads();
  #pragma unroll
  for (int i = 0; i < 16; ++i) {
    int idx = i*256 + t; int jc = idx >> 6, kr = idx & 63;
    int j  = j0 + jc;
    int n  = (j >> 2)*16 + (j & 3)*4 + gate;
    Wc[(size_t)n*KC + k0 + kr] = f2bf(tile[kr][jc]);
  }
}

__global__ void build_wfc(const float* __restrict__ Wfc, u16* __restrict__ WfcT)
{
  const int k0 = blockIdx.x * 64;
  const int n0 = blockIdx.y * 64;
  __shared__ float tile[64][65];
  const int t = threadIdx.x;
  #pragma unroll
  for (int i = 0; i < 16; ++i) {
    int idx = i*256 + t; int kr = idx >> 6, nc = idx & 63;
    tile[kr][nc] = Wfc[(size_t)(k0+kr)*OUTD + n0 + nc];
  }
  __syncthreads();
  #pragma unroll
  for (int i = 0; i < 16; ++i) {
    int idx = i*256 + t; int nc = idx >> 6, kr = idx & 63;
    WfcT[(size_t)(n0+nc)*2048 + k0 + kr] = f2bf(tile[kr][nc]);
  }
}

__global__ void conv_x(const float* __restrict__ x, u16* __restrict__ xb, int n)
{
  int i = (blockIdx.x * blockDim.x + threadIdx.x) * 4;
  if (i < n) {
    float4 v = *(const float4*)(x + i);
    u32 lo = (u32)f2bf(v.x) | ((u32)f2bf(v.y) << 16);
    u32 hi = (u32)f2bf(v.z) | ((u32)f2bf(v.w) << 16);
    *(uint2*)(xb + i) = make_uint2(lo, hi);
  }
}

// ---------------------------------------------------------------------------
// Persistent bidirectional LSTM: 512 blocks (256/dir, 4 h-cols each).
// 40KB LDS panel -> 2 blocks/CU co-resident (one F + one B by dispatch
// order): independent sync domains fill each other's poll stalls.
// hs2 layout IDENTICAL to r12: [t][dir][pair 0..127][row 0..63][4 u32];
// even block of a pair writes colpairs 0-1, odd writes 2-3.
// ---------------------------------------------------------------------------
__global__ __launch_bounds__(256, 2) void lstm_persist(
    const u16* __restrict__ WcF, const u16* __restrict__ WcB,
    const u16* __restrict__ xb,
    const float* __restrict__ bF, const float* __restrict__ bB,
    u32* __restrict__ hs2, float* __restrict__ out_tail, int* flags)
{
  extern __shared__ __align__(16) u16 Bs[];   // [NSL][64][8]

  // one-time: clear stale lines (poison / previous replay) from L1/L2
  __builtin_amdgcn_fence(__ATOMIC_ACQUIRE, "agent");

  const int bid = blockIdx.x;
  const int dir = bid >> 8;
  const int nb  = bid & 255;
  const int n0  = nb * 16;
  const int pr  = nb >> 1;          // hs2 pair index
  const int sub = nb & 1;           // colpair offset 0 / 2
  const u16* __restrict__ Wc   = dir ? WcB : WcF;
  const float* __restrict__ bias = dir ? bB : bF;

  const int tid  = threadIdx.x;
  const int w    = tid >> 6, lane = tid & 63;
  const int r    = lane & 15, q = lane >> 4, rq = r >> 2;
  int* __restrict__ fl = flags + (dir * 4 + w) * DBLK;
  const u64* __restrict__ fl64 = (const u64*)fl;

  // stage B panel into LDS: chunk c -> [ks][lane] 16B
  for (int c = tid; c < NSL * 64; c += 256) {
    int ks = c >> 6, l = c & 63;
    *(short8*)&Bs[(size_t)c * 8] =
        *(const short8*)(Wc + (size_t)(n0 + (l & 15)) * KC + ks*32 + (l >> 4)*8);
  }
  #define BSF(ks) (*(const short8*)&Bs[((size_t)((ks)*64 + lane))*8])

  const int jcol = nb * 4 + rq;     // this lane's h-col (writer lanes r&3==0)
  float bia[4];
  #pragma unroll
  for (int g = 0; g < 4; ++g) bia[g] = bias[g * HID + jcol];

  float creg[4] = {0.f, 0.f, 0.f, 0.f};

  const int row_a = w * 16 + r;

  // prefetch x fragments for step 0
  short8 xf[8];
  {
    const int tt0 = dir ? (T_SEQ - 1) : 0;
    const u16* axr = xb + ((size_t)tt0 * BATCH + row_a) * INP;
    #pragma unroll
    for (int kx = 0; kx < 8; ++kx) xf[kx] = *(const short8*)(axr + kx*32 + q*8);
  }
  __syncthreads();   // Bs staged (only block-wide barrier)

  // x-part MFMAs of step 0 (tail-issued structure)
  f32x4 accA = (f32x4)(0.f), accB = (f32x4)(0.f);
  #pragma unroll
  for (int kx = 0; kx < 8; ++kx) accA = MFMA16(xf[kx], BSF(32 + kx), accA);

  u64 pf0 = 0, pf1 = 0;   // primed flag values (4 flags/lane)

  for (int s = 0; s < T_SEQ; ++s) {
    const int tt = dir ? (T_SEQ - 1 - s) : s;

    if (s > 0) {
      // wait for all 256 wave-w producers of step s-1 (pf primed last iter)
      while (true) {
        int ok = ((int)(pf0 & 0xffffffffu) >= s) && ((int)(pf0 >> 32) >= s) &&
                 ((int)(pf1 & 0xffffffffu) >= s) && ((int)(pf1 >> 32) >= s);
        if (__all(ok)) break;
        pf0 = ag_ld_u64(fl64 + lane);
        pf1 = ag_ld_u64(fl64 + 64 + lane);
      }
      const int tp = dir ? tt + 1 : tt - 1;
      // A-fragment: pair q of each slice-group, this lane's row (same as r12)
      const u32* __restrict__ ar =
          hs2 + (((size_t)(tp * 2 + dir) * 128 + q) * 64 + row_a) * 4;
      short8 hA[32];
      #pragma unroll
      for (int i = 0; i < 32; ++i)
        hA[i] = *(const short8*)(ar + (size_t)i * 1024);   // +4 pairs/slice
      #pragma unroll
      for (int i = 0; i < 16; ++i) {
        accA = MFMA16(hA[i],      BSF(i),      accA);
        accB = MFMA16(hA[16 + i], BSF(16 + i), accB);
      }
    }

    // merge chains + cell update (DPP quad gather; gate = r&3)
    float hnv[4];
    #pragma unroll
    for (int rg = 0; rg < 4; ++rg) {
      float v  = accA[rg] + accB[rg];
      float x1 = qperm<QP_XOR1>(v);
      float x2 = qperm<QP_XOR2>(v);
      float x3 = qperm<QP_XOR2>(x1);
      float cn = sigm(x1 + bia[1]) * creg[rg] + sigm(v + bia[0]) * tanhf_(x3 + bia[3]);
      float hn = sigm(x2 + bia[2]) * tanhf_(cn);
      creg[rg] = cn; hnv[rg] = hn;
    }
    // pack col pairs via lane^4 swizzle; writers r in {0,8} store one u32 each
    {
      u32* base = hs2 + (((size_t)(tt * 2 + dir) * 128 + pr) * 64 + w*16 + q*4) * 4
                      + sub * 2 + (r >> 3);
      #pragma unroll
      for (int rg = 0; rg < 4; ++rg) {
        u32 v32 = (u32)f2bf(hnv[rg]);
        u32 ot  = (u32)__builtin_amdgcn_ds_swizzle((int)v32, 0x101F);  // lane^4
        if ((r & 7) == 0)
          ag_st_u32(base + rg * 4, v32 | (ot << 16));
      }
    }

    if (s < T_SEQ - 1) {
      asm volatile("s_waitcnt vmcnt(0)" ::: "memory");   // h stores at IC
      if (lane == 0) ag_st_u32((u32*)(fl + nb), (u32)(s + 1));
      // issue next step's x loads + prime flag loads + x-MFMAs (tail):
      // latency overlaps flag propagation; co-resident other-dir block
      // fills the remaining stall.
      const int tn = dir ? tt - 1 : tt + 1;
      const u16* axr = xb + ((size_t)tn * BATCH + row_a) * INP;
      #pragma unroll
      for (int kx = 0; kx < 8; ++kx) xf[kx] = *(const short8*)(axr + kx*32 + q*8);
      pf0 = ag_ld_u64(fl64 + lane);
      pf1 = ag_ld_u64(fl64 + 64 + lane);
      accA = (f32x4)(0.f); accB = (f32x4)(0.f);
      #pragma unroll
      for (int kx = 0; kx < 8; ++kx) accA = MFMA16(xf[kx], BSF(32 + kx), accA);
    } else {
      // final states ((hF,hB),(cF,cB)); plain stores (kernel-end flush)
      if ((r & 3) == 0) {
        #pragma unroll
        for (int rg = 0; rg < 4; ++rg) {
          int row = w * 16 + q * 4 + rg;
          out_tail[dir * (BATCH * HID) + (size_t)row * HID + jcol] = hnv[rg];
          out_tail[2 * (BATCH * HID) + dir * (BATCH * HID) + (size_t)row * HID + jcol] = creg[rg];
        }
      }
    }
  }
  #undef BSF
}

// ---------------------------------------------------------------------------
// Final FC: out[16384][1024] = H @ WfcT^T + b_fc, H read from hs2 layout.
// hs2[t][dir][pair][row][4 u32]: k = dir*1024 + pair*8 + c.
// ---------------------------------------------------------------------------
__global__ __launch_bounds__(256) void fc_kernel(
    const u32* __restrict__ hs2, const u16* __restrict__ WfcT,
    const float* __restrict__ bfc, float* __restrict__ out)
{
  const int m0 = blockIdx.x * 128, n0 = blockIdx.y * 128;
  __shared__ __align__(16) u16 As[128 * 32];
  __shared__ __align__(16) u16 Bs[128 * 32];
  const int tid = threadIdx.x;
  const int w = tid >> 6, lane = tid & 63;
  const int r = lane & 15, q = lane >> 4;
  const int wy = w >> 1, wx = w & 1;

  f32x4 acc[4][4];
  #pragma unroll
  for (int a = 0; a < 4; ++a)
    #pragma unroll
    for (int b = 0; b < 4; ++b) acc[a][b] = (f32x4)(0.f);

  const int lr = tid >> 1, lk = (tid & 1) * 16;

  for (int k0 = 0; k0 < 2048; k0 += 32) {
    __syncthreads();
    {
      int m = m0 + lr; int t = m >> 6, row = m & 63;
      int k = k0 + lk; int d = k >> 10, kk = k & 1023; int p2 = kk >> 3;
      const u32* p = hs2 + (((size_t)(t * 2 + d) * 128 + p2) * 64 + row) * 4;
      *(short8*)&As[lr * 32 + lk]     = *(const short8*)p;
      *(short8*)&As[lr * 32 + lk + 8] = *(const short8*)(p + 256);  // pair+1
    }
    *(short8*)&Bs[lr * 32 + lk]     = *(const short8*)(WfcT + (size_t)(n0 + lr) * 2048 + k0 + lk);
    *(short8*)&Bs[lr * 32 + lk + 8] = *(const short8*)(WfcT + (size_t)(n0 + lr) * 2048 + k0 + lk + 8);
    __syncthreads();

    short8 af[4], bf[4];
    #pragma unroll
    for (int mt = 0; mt < 4; ++mt)
      af[mt] = *(const short8*)&As[(wy * 64 + mt * 16 + r) * 32 + q * 8];
    #pragma unroll
    for (int nt = 0; nt < 4; ++nt)
      bf[nt] = *(const short8*)&Bs[(wx * 64 + nt * 16 + r) * 32 + q * 8];
    #pragma unroll
    for (int mt = 0; mt < 4; ++mt)
      #pragma unroll
      for (int nt = 0; nt < 4; ++nt)
        acc[mt][nt] = __builtin_amdgcn_mfma_f32_16x16x32_bf16(af[mt], bf[nt], acc[mt][nt], 0, 0, 0);
  }

  #pragma unroll
  for (int mt = 0; mt < 4; ++mt)
    #pragma unroll
    for (int nt = 0; nt < 4; ++nt)
      #pragma unroll
      for (int reg = 0; reg < 4; ++reg) {
        int m = m0 + wy * 64 + mt * 16 + q * 4 + reg;
        int n = n0 + wx * 64 + nt * 16 + r;
        out[(size_t)m * OUTD + n] = acc[mt][nt][reg] + bfc[n];
      }
}

// ---------------------------------------------------------------------------
extern "C" void kernel_launch(void* const* d_in, const int* in_sizes, int n_in,
                              void* d_out, int out_size, void* d_ws, size_t ws_size,
                              hipStream_t stream)
{
  const float* x   = (const float*)d_in[0];
  const float* WxF = (const float*)d_in[1];
  const float* WhF = (const float*)d_in[2];
  const float* bF  = (const float*)d_in[3];
  const float* WxB = (const float*)d_in[4];
  const float* WhB = (const float*)d_in[5];
  const float* bB  = (const float*)d_in[6];
  const float* Wfc = (const float*)d_in[7];
  const float* bfc = (const float*)d_in[8];
  float* out = (float*)d_out;

  char* ws = (char*)d_ws;
  u16*  WcF   = (u16*)(ws + 0);          // 10485760
  u16*  WcB   = (u16*)(ws + 10485760);   // 10485760
  u16*  WfcT  = (u16*)(ws + 20971520);   // 4194304
  u16*  xb    = (u16*)(ws + 25165824);   // 8388608
  u32*  hs2   = (u32*)(ws + 34603008);   // 67108864 (t,dir,pair,row,4xu32)
  int*  flags = (int*)(ws + 101711872);  // 8KB (2 dirs x 4 waves x 256)

  hipMemsetAsync(flags, 0, 8192, stream);   // barrier flags

  hipFuncSetAttribute((const void*)lstm_persist,
                      hipFuncAttributeMaxDynamicSharedMemorySize, LDSB);

  build_wc <<<dim3(KC/64, HID/64, 8), 256, 0, stream>>>(WhF, WxF, WhB, WxB, WcF, WcB);
  build_wfc<<<dim3(2048/64, OUTD/64), 256, 0, stream>>>(Wfc, WfcT);
  conv_x   <<<(T_SEQ*BATCH*INP)/4/256, 256, 0, stream>>>(x, xb, T_SEQ*BATCH*INP);

  lstm_persist<<<NBLK, 256, LDSB, stream>>>(WcF, WcB, xb, bF, bB,
                                            hs2, out + 16777216, flags);

  fc_kernel<<<dim3(16384/128, OUTD/128), 256, 0, stream>>>(hs2, WfcT, bfc, out);
}

// Round 14
// 2651.561 us; speedup vs baseline: 1.9068x; 1.9068x over previous
//
#include <hip/hip_runtime.h>

using short8 = __attribute__((ext_vector_type(8))) short;
using f32x4  = __attribute__((ext_vector_type(4))) float;

typedef unsigned short u16;
typedef unsigned int   u32;
typedef unsigned long long u64;

#define T_SEQ 256
#define BATCH 64
#define INP   256
#define HID   1024
#define GDIM  4096
#define KC    1280   // HID + INP
#define OUTD  1024

#define NSL   40     // K slices of 32 (32 h + 8 x)
#define NBLK  256
#define DBLK  128    // blocks per direction
#define LDSB  (NSL * 2 * 64 * 8 * 2)   // 81920 bytes dynamic LDS

#define MFMA16(a,b,c) __builtin_amdgcn_mfma_f32_16x16x32_bf16(a,b,c,0,0,0)

__device__ __forceinline__ u16 f2bf(float f){
  union { float f; u32 u; } v; v.f = f;
  u32 r = v.u + 0x7fffu + ((v.u >> 16) & 1u);
  return (u16)(r >> 16);
}
__device__ __forceinline__ float sigm(float x){ return 1.f/(1.f+__expf(-x)); }
__device__ __forceinline__ float tanhf_(float x){ return 1.f - 2.f/(__expf(2.f*x)+1.f); }

// agent-scope (device-coherent, IC-resident) ops — compiler emits sc1
__device__ __forceinline__ void ag_st_u32(u32* p, u32 v){
  __hip_atomic_store(p, v, __ATOMIC_RELAXED, __HIP_MEMORY_SCOPE_AGENT);
}
__device__ __forceinline__ u64 ag_ld_u64(const u64* p){
  return __hip_atomic_load(p, __ATOMIC_RELAXED, __HIP_MEMORY_SCOPE_AGENT);
}

// quad-perm DPP: 4 gates of one h-col live in one lane-quad
template<int CTRL>
__device__ __forceinline__ float qperm(float v){
  union { float f; int i; } u; u.f = v;
  u.i = __builtin_amdgcn_mov_dpp(u.i, CTRL, 0xf, 0xf, true);
  return u.f;
}
#define QP_XOR1 177   // quad_perm [1,0,3,2]
#define QP_XOR2 78    // quad_perm [2,3,0,1]

// ---------------------------------------------------------------------------
// Prep: combined recurrent weights, bf16, block-permuted column order.
// Block nb owns gate-cols [nb*32, nb*32+32); n = nb*32 + nt*16 + rq*4 + gate,
// h-col j = nb*8 + 2*rq + nt. Rows k<1024 -> Wh, k>=1024 -> Wx.
// ---------------------------------------------------------------------------
__global__ void build_wc(const float* __restrict__ WhF, const float* __restrict__ WxF,
                         const float* __restrict__ WhB, const float* __restrict__ WxB,
                         u16* __restrict__ WcF, u16* __restrict__ WcB)
{
  const int z = blockIdx.z; const int dir = z >> 2, gate = z & 3;
  const float* Wh = dir ? WhB : WhF;
  const float* Wx = dir ? WxB : WxF;
  u16* Wc = dir ? WcB : WcF;
  const int k0 = blockIdx.x * 64, j0 = blockIdx.y * 64;
  __shared__ float tile[64][65];
  const int t = threadIdx.x;
  #pragma unroll
  for (int i = 0; i < 16; ++i) {
    int idx = i*256 + t; int kr = idx >> 6, jc = idx & 63;
    int k = k0 + kr;
    float v = (k < HID) ? Wh[(size_t)k*GDIM + gate*HID + j0 + jc]
                        : Wx[(size_t)(k-HID)*GDIM + gate*HID + j0 + jc];
    tile[kr][jc] = v;
  }
  __syncthreads();
  #pragma unroll
  for (int i = 0; i < 16; ++i) {
    int idx = i*256 + t; int jc = idx >> 6, kr = idx & 63;
    int j  = j0 + jc;
    int nb = j >> 3, jl = j & 7;
    int nt = jl & 1, rq = jl >> 1;
    int n  = nb*32 + nt*16 + rq*4 + gate;
    Wc[(size_t)n*KC + k0 + kr] = f2bf(tile[kr][jc]);
  }
}

__global__ void build_wfc(const float* __restrict__ Wfc, u16* __restrict__ WfcT)
{
  const int k0 = blockIdx.x * 64;
  const int n0 = blockIdx.y * 64;
  __shared__ float tile[64][65];
  const int t = threadIdx.x;
  #pragma unroll
  for (int i = 0; i < 16; ++i) {
    int idx = i*256 + t; int kr = idx >> 6, nc = idx & 63;
    tile[kr][nc] = Wfc[(size_t)(k0+kr)*OUTD + n0 + nc];
  }
  __syncthreads();
  #pragma unroll
  for (int i = 0; i < 16; ++i) {
    int idx = i*256 + t; int nc = idx >> 6, kr = idx & 63;
    WfcT[(size_t)(n0+nc)*2048 + k0 + kr] = f2bf(tile[kr][nc]);
  }
}

__global__ void conv_x(const float* __restrict__ x, u16* __restrict__ xb, int n)
{
  int i = (blockIdx.x * blockDim.x + threadIdx.x) * 4;
  if (i < n) {
    float4 v = *(const float4*)(x + i);
    u32 lo = (u32)f2bf(v.x) | ((u32)f2bf(v.y) << 16);
    u32 hi = (u32)f2bf(v.z) | ((u32)f2bf(v.w) << 16);
    *(uint2*)(xb + i) = make_uint2(lo, hi);
  }
}

// ---------------------------------------------------------------------------
// Persistent bidirectional LSTM (r12 champion + group-gated consumption).
// hs2[t][dir][nb][row 0..63][4 u32]: block-contiguous 1KB step regions.
// K-slice ks reads only producers 4ks..4ks+3 -> group g (slices 4g..4g+3)
// gates on producers 16g..16g+15 via 8 ballot bits; depth-4 load pipeline.
// Steady state == r12 schedule; stragglers stall only their own group.
// ---------------------------------------------------------------------------
__global__ __launch_bounds__(256, 1) void lstm_persist(
    const u16* __restrict__ WcF, const u16* __restrict__ WcB,
    const u16* __restrict__ xb,
    const float* __restrict__ bF, const float* __restrict__ bB,
    u32* __restrict__ hs2, float* __restrict__ out_tail, int* flags)
{
  extern __shared__ __align__(16) u16 Bs[];   // [NSL][2][64][8]

  // one-time: clear stale lines (poison / previous replay) from L1/L2
  __builtin_amdgcn_fence(__ATOMIC_ACQUIRE, "agent");

  const int bid = blockIdx.x;
  const int dir = bid >> 7;
  const int nb  = bid & 127;
  const int n0  = nb * 32;
  const u16* __restrict__ Wc   = dir ? WcB : WcF;
  const float* __restrict__ bias = dir ? bB : bF;

  const int tid  = threadIdx.x;
  const int w    = tid >> 6, lane = tid & 63;
  const int r    = lane & 15, q = lane >> 4, rq = r >> 2;
  int* __restrict__ fl = flags + (dir * 4 + w) * DBLK;
  const u64* __restrict__ fl64 = (const u64*)fl;

  // stage B panel into LDS: chunk c -> [ks][nt][lane] 16B
  for (int c = tid; c < NSL * 128; c += 256) {
    int ks  = c >> 7;
    int rem = c & 127;
    int nt  = rem >> 6, l2 = rem & 63;
    *(short8*)&Bs[(size_t)c * 8] =
        *(const short8*)(Wc + (size_t)(n0 + nt*16 + (l2 & 15)) * KC + ks*32 + (l2 >> 4)*8);
  }
  #define BSF(ks, nt) (*(const short8*)&Bs[((size_t)(((ks)*2 + (nt))*64 + lane))*8])

  const int jbase = nb * 8;
  float bia[2][4];
  #pragma unroll
  for (int nt = 0; nt < 2; ++nt)
    #pragma unroll
    for (int g = 0; g < 4; ++g)
      bia[nt][g] = bias[g * HID + jbase + 2*rq + nt];

  float creg[2][4];
  #pragma unroll
  for (int nt = 0; nt < 2; ++nt)
    #pragma unroll
    for (int rg = 0; rg < 4; ++rg) creg[nt][rg] = 0.f;

  const int row_a = w * 16 + r;

  // prefetch x fragments for step 0
  short8 xf[8];
  {
    const int tt0 = dir ? (T_SEQ - 1) : 0;
    const u16* axr = xb + ((size_t)tt0 * BATCH + row_a) * INP;
    #pragma unroll
    for (int kx = 0; kx < 8; ++kx) xf[kx] = *(const short8*)(axr + kx*32 + q*8);
  }
  __syncthreads();   // Bs staged (only block-wide barrier)

  // x-part MFMAs of step 0 (tail-issued structure)
  f32x4 accA[2], accB[2];
  accA[0] = (f32x4)(0.f); accA[1] = (f32x4)(0.f);
  accB[0] = (f32x4)(0.f); accB[1] = (f32x4)(0.f);
  #pragma unroll
  for (int kx = 0; kx < 8; ++kx) {
    accA[0] = MFMA16(xf[kx], BSF(32 + kx, 0), accA[0]);
    accA[1] = MFMA16(xf[kx], BSF(32 + kx, 1), accA[1]);
  }

  u64 pf = 0;   // primed flag-pair value (blocks 2*lane, 2*lane+1)

  #define WAITG(g) \
    while (((bal >> (8*(g))) & 0xffull) != 0xffull) { \
      pf  = ag_ld_u64(fl64 + lane); \
      okv = ((int)(pf & 0xffffffffu) >= s) && ((int)(pf >> 32) >= s); \
      bal = __ballot(okv); \
    }
  #define LOADG(B, g) \
    B[0] = *(const short8*)(ar + (size_t)((g)*4 + 0) * 1024); \
    B[1] = *(const short8*)(ar + (size_t)((g)*4 + 1) * 1024); \
    B[2] = *(const short8*)(ar + (size_t)((g)*4 + 2) * 1024); \
    B[3] = *(const short8*)(ar + (size_t)((g)*4 + 3) * 1024);
  #define MFMAG(B, g) \
    accA[0] = MFMA16(B[0], BSF((g)*4 + 0, 0), accA[0]); \
    accA[1] = MFMA16(B[0], BSF((g)*4 + 0, 1), accA[1]); \
    accB[0] = MFMA16(B[1], BSF((g)*4 + 1, 0), accB[0]); \
    accB[1] = MFMA16(B[1], BSF((g)*4 + 1, 1), accB[1]); \
    accA[0] = MFMA16(B[2], BSF((g)*4 + 2, 0), accA[0]); \
    accA[1] = MFMA16(B[2], BSF((g)*4 + 2, 1), accA[1]); \
    accB[0] = MFMA16(B[3], BSF((g)*4 + 3, 0), accB[0]); \
    accB[1] = MFMA16(B[3], BSF((g)*4 + 3, 1), accB[1]);

  for (int s = 0; s < T_SEQ; ++s) {
    const int tt = dir ? (T_SEQ - 1 - s) : s;

    if (s > 0) {
      int okv = ((int)(pf & 0xffffffffu) >= s) && ((int)(pf >> 32) >= s);
      u64 bal = __ballot(okv);
      const int tp = dir ? tt + 1 : tt - 1;
      const u32* __restrict__ ar =
          hs2 + (((size_t)(tp * 2 + dir) * 128 + q) * 64 + row_a) * 4;
      short8 B0[4], B1[4], B2[4], B3[4];
      WAITG(0) LOADG(B0, 0)
      WAITG(1) LOADG(B1, 1)
      WAITG(2) LOADG(B2, 2)
      WAITG(3) LOADG(B3, 3)
      MFMAG(B0, 0) WAITG(4) LOADG(B0, 4)
      MFMAG(B1, 1) WAITG(5) LOADG(B1, 5)
      MFMAG(B2, 2) WAITG(6) LOADG(B2, 6)
      MFMAG(B3, 3) WAITG(7) LOADG(B3, 7)
      MFMAG(B0, 4)
      MFMAG(B1, 5)
      MFMAG(B2, 6)
      MFMAG(B3, 7)
    }

    // merge chains + cell update (DPP quad gather; gate = r&3)
    float hnv[2][4];
    #pragma unroll
    for (int nt = 0; nt < 2; ++nt) {
      #pragma unroll
      for (int rg = 0; rg < 4; ++rg) {
        float v  = accA[nt][rg] + accB[nt][rg];
        float x1 = qperm<QP_XOR1>(v);
        float x2 = qperm<QP_XOR2>(v);
        float x3 = qperm<QP_XOR2>(x1);
        float cn = sigm(x1 + bia[nt][1]) * creg[nt][rg] + sigm(v + bia[nt][0]) * tanhf_(x3 + bia[nt][3]);
        float hn = sigm(x2 + bia[nt][2]) * tanhf_(cn);
        creg[nt][rg] = cn; hnv[nt][rg] = hn;
      }
    }
    // packed u32 agent stores into the block-contiguous region:
    // hs2[tt][dir][nb][row = w*16+q*4+rg][colpair rq]
    if ((r & 3) == 0) {
      u32* base = hs2 + (((size_t)(tt * 2 + dir) * 128 + nb) * 64 + w*16 + q*4) * 4 + rq;
      #pragma unroll
      for (int rg = 0; rg < 4; ++rg) {
        u32 packed = (u32)f2bf(hnv[0][rg]) | ((u32)f2bf(hnv[1][rg]) << 16);
        ag_st_u32(base + rg * 4, packed);
      }
    }

    if (s < T_SEQ - 1) {
      asm volatile("s_waitcnt vmcnt(0)" ::: "memory");   // h stores at IC
      if (lane == 0) ag_st_u32((u32*)(fl + nb), (u32)(s + 1));
      // issue next step's x loads + prime flag load + x-MFMAs (tail):
      // their latency overlaps the flag propagation of other blocks.
      const int tn = dir ? tt - 1 : tt + 1;
      const u16* axr = xb + ((size_t)tn * BATCH + row_a) * INP;
      #pragma unroll
      for (int kx = 0; kx < 8; ++kx) xf[kx] = *(const short8*)(axr + kx*32 + q*8);
      pf = ag_ld_u64(fl64 + lane);
      accA[0] = (f32x4)(0.f); accA[1] = (f32x4)(0.f);
      accB[0] = (f32x4)(0.f); accB[1] = (f32x4)(0.f);
      #pragma unroll
      for (int kx = 0; kx < 8; ++kx) {
        accA[0] = MFMA16(xf[kx], BSF(32 + kx, 0), accA[0]);
        accA[1] = MFMA16(xf[kx], BSF(32 + kx, 1), accA[1]);
      }
    } else {
      // final states ((hF,hB),(cF,cB)); plain stores (kernel-end flush)
      if ((r & 3) == 0) {
        #pragma unroll
        for (int nt = 0; nt < 2; ++nt)
          #pragma unroll
          for (int rg = 0; rg < 4; ++rg) {
            int row = w * 16 + q * 4 + rg;
            int j   = jbase + 2*rq + nt;
            out_tail[dir * (BATCH * HID) + (size_t)row * HID + j] = hnv[nt][rg];
            out_tail[2 * (BATCH * HID) + dir * (BATCH * HID) + (size_t)row * HID + j] = creg[nt][rg];
          }
      }
    }
  }
  #undef BSF
  #undef WAITG
  #undef LOADG
  #undef MFMAG
}

// ---------------------------------------------------------------------------
// Final FC: out[16384][1024] = H @ WfcT^T + b_fc, H read from hs2 layout.
// hs2[t][dir][nb][row][4 u32]: k = dir*1024 + nb*8 + c.
// ---------------------------------------------------------------------------
__global__ __launch_bounds__(256) void fc_kernel(
    const u32* __restrict__ hs2, const u16* __restrict__ WfcT,
    const float* __restrict__ bfc, float* __restrict__ out)
{
  const int m0 = blockIdx.x * 128, n0 = blockIdx.y * 128;
  __shared__ __align__(16) u16 As[128 * 32];
  __shared__ __align__(16) u16 Bs[128 * 32];
  const int tid = threadIdx.x;
  const int w = tid >> 6, lane = tid & 63;
  const int r = lane & 15, q = lane >> 4;
  const int wy = w >> 1, wx = w & 1;

  f32x4 acc[4][4];
  #pragma unroll
  for (int a = 0; a < 4; ++a)
    #pragma unroll
    for (int b = 0; b < 4; ++b) acc[a][b] = (f32x4)(0.f);

  const int lr = tid >> 1, lk = (tid & 1) * 16;

  for (int k0 = 0; k0 < 2048; k0 += 32) {
    __syncthreads();
    {
      int m = m0 + lr; int t = m >> 6, row = m & 63;
      int k = k0 + lk; int d = k >> 10, kk = k & 1023; int nb2 = kk >> 3;
      const u32* p = hs2 + (((size_t)(t * 2 + d) * 128 + nb2) * 64 + row) * 4;
      *(short8*)&As[lr * 32 + lk]     = *(const short8*)p;
      *(short8*)&As[lr * 32 + lk + 8] = *(const short8*)(p + 256);  // nb2+1
    }
    *(short8*)&Bs[lr * 32 + lk]     = *(const short8*)(WfcT + (size_t)(n0 + lr) * 2048 + k0 + lk);
    *(short8*)&Bs[lr * 32 + lk + 8] = *(const short8*)(WfcT + (size_t)(n0 + lr) * 2048 + k0 + lk + 8);
    __syncthreads();

    short8 af[4], bf[4];
    #pragma unroll
    for (int mt = 0; mt < 4; ++mt)
      af[mt] = *(const short8*)&As[(wy * 64 + mt * 16 + r) * 32 + q * 8];
    #pragma unroll
    for (int nt = 0; nt < 4; ++nt)
      bf[nt] = *(const short8*)&Bs[(wx * 64 + nt * 16 + r) * 32 + q * 8];
    #pragma unroll
    for (int mt = 0; mt < 4; ++mt)
      #pragma unroll
      for (int nt = 0; nt < 4; ++nt)
        acc[mt][nt] = __builtin_amdgcn_mfma_f32_16x16x32_bf16(af[mt], bf[nt], acc[mt][nt], 0, 0, 0);
  }

  #pragma unroll
  for (int mt = 0; mt < 4; ++mt)
    #pragma unroll
    for (int nt = 0; nt < 4; ++nt)
      #pragma unroll
      for (int reg = 0; reg < 4; ++reg) {
        int m = m0 + wy * 64 + mt * 16 + q * 4 + reg;
        int n = n0 + wx * 64 + nt * 16 + r;
        out[(size_t)m * OUTD + n] = acc[mt][nt][reg] + bfc[n];
      }
}

// ---------------------------------------------------------------------------
extern "C" void kernel_launch(void* const* d_in, const int* in_sizes, int n_in,
                              void* d_out, int out_size, void* d_ws, size_t ws_size,
                              hipStream_t stream)
{
  const float* x   = (const float*)d_in[0];
  const float* WxF = (const float*)d_in[1];
  const float* WhF = (const float*)d_in[2];
  const float* bF  = (const float*)d_in[3];
  const float* WxB = (const float*)d_in[4];
  const float* WhB = (const float*)d_in[5];
  const float* bB  = (const float*)d_in[6];
  const float* Wfc = (const float*)d_in[7];
  const float* bfc = (const float*)d_in[8];
  float* out = (float*)d_out;

  char* ws = (char*)d_ws;
  u16*  WcF   = (u16*)(ws + 0);          // 10485760
  u16*  WcB   = (u16*)(ws + 10485760);   // 10485760
  u16*  WfcT  = (u16*)(ws + 20971520);   // 4194304
  u16*  xb    = (u16*)(ws + 25165824);   // 8388608
  u32*  hs2   = (u32*)(ws + 34603008);   // 67108864 (t,dir,nb,row,4xu32)
  int*  flags = (int*)(ws + 101711872);  // 4KB (2 dirs x 4 waves x 128)

  hipMemsetAsync(flags, 0, 4096, stream);   // barrier flags

  hipFuncSetAttribute((const void*)lstm_persist,
                      hipFuncAttributeMaxDynamicSharedMemorySize, LDSB);

  build_wc <<<dim3(KC/64, HID/64, 8), 256, 0, stream>>>(WhF, WxF, WhB, WxB, WcF, WcB);
  build_wfc<<<dim3(2048/64, OUTD/64), 256, 0, stream>>>(Wfc, WfcT);
  conv_x   <<<(T_SEQ*BATCH*INP)/4/256, 256, 0, stream>>>(x, xb, T_SEQ*BATCH*INP);

  lstm_persist<<<NBLK, 256, LDSB, stream>>>(WcF, WcB, xb, bF, bB,
                                            hs2, out + 16777216, flags);

  fc_kernel<<<dim3(16384/128, OUTD/128), 256, 0, stream>>>(hs2, WfcT, bfc, out);
}

// Round 16
// 2513.980 us; speedup vs baseline: 2.0111x; 1.0547x over previous
//
#include <hip/hip_runtime.h>

using short8 = __attribute__((ext_vector_type(8))) short;
using f32x4  = __attribute__((ext_vector_type(4))) float;
using u32x4  = __attribute__((ext_vector_type(4))) unsigned int;

typedef unsigned short u16;
typedef unsigned int   u32;
typedef unsigned long long u64;

#define T_SEQ 256
#define BATCH 64
#define INP   256
#define HID   1024
#define GDIM  4096
#define KC    1280   // HID + INP
#define OUTD  1024

#define NSL   40     // K slices of 32 (32 h + 8 x)
#define NBLK  256
#define DBLK  128    // blocks per direction
#define LDSB  (NSL * 2 * 64 * 8 * 2)   // 81920 bytes dynamic LDS

#define MFMA16(a,b,c) __builtin_amdgcn_mfma_f32_16x16x32_bf16(a,b,c,0,0,0)

__device__ __forceinline__ u16 f2bf(float f){
  union { float f; u32 u; } v; v.f = f;
  u32 r = v.u + 0x7fffu + ((v.u >> 16) & 1u);
  return (u16)(r >> 16);
}
__device__ __forceinline__ float sigm(float x){ return 1.f/(1.f+__expf(-x)); }
__device__ __forceinline__ float tanhf_(float x){ return 1.f - 2.f/(__expf(2.f*x)+1.f); }

// agent-scope (device-coherent, IC-resident) ops — sc1
__device__ __forceinline__ void ag_st_u32(u32* p, u32 v){
  __hip_atomic_store(p, v, __ATOMIC_RELAXED, __HIP_MEMORY_SCOPE_AGENT);
}
__device__ __forceinline__ void ag_st_u32x4(u32* p, u32x4 v){
  asm volatile("global_store_dwordx4 %0, %1, off sc1" :: "v"(p), "v"(v) : "memory");
}
__device__ __forceinline__ u64 ag_ld_u64(const u64* p){
  return __hip_atomic_load(p, __ATOMIC_RELAXED, __HIP_MEMORY_SCOPE_AGENT);
}

// quad-perm DPP: 4 gates of one h-col live in one lane-quad
template<int CTRL>
__device__ __forceinline__ float qperm(float v){
  union { float f; int i; } u; u.f = v;
  u.i = __builtin_amdgcn_mov_dpp(u.i, CTRL, 0xf, 0xf, true);
  return u.f;
}
#define QP_XOR1 177   // quad_perm [1,0,3,2]
#define QP_XOR2 78    // quad_perm [2,3,0,1]

// ---------------------------------------------------------------------------
// Prep: combined recurrent weights, bf16, block-permuted column order.
// Block nb owns gate-cols [nb*32, nb*32+32); n = nb*32 + nt*16 + rq*4 + gate,
// h-col j = nb*8 + 2*rq + nt. Rows k<1024 -> Wh, k>=1024 -> Wx.
// ---------------------------------------------------------------------------
__global__ void build_wc(const float* __restrict__ WhF, const float* __restrict__ WxF,
                         const float* __restrict__ WhB, const float* __restrict__ WxB,
                         u16* __restrict__ WcF, u16* __restrict__ WcB)
{
  const int z = blockIdx.z; const int dir = z >> 2, gate = z & 3;
  const float* Wh = dir ? WhB : WhF;
  const float* Wx = dir ? WxB : WxF;
  u16* Wc = dir ? WcB : WcF;
  const int k0 = blockIdx.x * 64, j0 = blockIdx.y * 64;
  __shared__ float tile[64][65];
  const int t = threadIdx.x;
  #pragma unroll
  for (int i = 0; i < 16; ++i) {
    int idx = i*256 + t; int kr = idx >> 6, jc = idx & 63;
    int k = k0 + kr;
    float v = (k < HID) ? Wh[(size_t)k*GDIM + gate*HID + j0 + jc]
                        : Wx[(size_t)(k-HID)*GDIM + gate*HID + j0 + jc];
    tile[kr][jc] = v;
  }
  __syncthreads();
  #pragma unroll
  for (int i = 0; i < 16; ++i) {
    int idx = i*256 + t; int jc = idx >> 6, kr = idx & 63;
    int j  = j0 + jc;
    int nb = j >> 3, jl = j & 7;
    int nt = jl & 1, rq = jl >> 1;
    int n  = nb*32 + nt*16 + rq*4 + gate;
    Wc[(size_t)n*KC + k0 + kr] = f2bf(tile[kr][jc]);
  }
}

__global__ void build_wfc(const float* __restrict__ Wfc, u16* __restrict__ WfcT)
{
  const int k0 = blockIdx.x * 64;
  const int n0 = blockIdx.y * 64;
  __shared__ float tile[64][65];
  const int t = threadIdx.x;
  #pragma unroll
  for (int i = 0; i < 16; ++i) {
    int idx = i*256 + t; int kr = idx >> 6, nc = idx & 63;
    tile[kr][nc] = Wfc[(size_t)(k0+kr)*OUTD + n0 + nc];
  }
  __syncthreads();
  #pragma unroll
  for (int i = 0; i < 16; ++i) {
    int idx = i*256 + t; int nc = idx >> 6, kr = idx & 63;
    WfcT[(size_t)(n0+nc)*2048 + k0 + kr] = f2bf(tile[kr][nc]);
  }
}

__global__ void conv_x(const float* __restrict__ x, u16* __restrict__ xb, int n)
{
  int i = (blockIdx.x * blockDim.x + threadIdx.x) * 4;
  if (i < n) {
    float4 v = *(const float4*)(x + i);
    u32 lo = (u32)f2bf(v.x) | ((u32)f2bf(v.y) << 16);
    u32 hi = (u32)f2bf(v.z) | ((u32)f2bf(v.w) << 16);
    *(uint2*)(xb + i) = make_uint2(lo, hi);
  }
}

// ---------------------------------------------------------------------------
// Persistent bidirectional LSTM (r14 + coalesced LDS-staged h stores +
// pipelined flag poll). hs2[t][dir][nb][row 0..63][4 u32]: block-contiguous
// 1KB step regions. Group-gated consumption (K-slice ks needs producers
// 4ks..4ks+3 only); flags monotonic -> ballots OR-accumulate.
// ---------------------------------------------------------------------------
__global__ __launch_bounds__(256, 1) void lstm_persist(
    const u16* __restrict__ WcF, const u16* __restrict__ WcB,
    const u16* __restrict__ xb,
    const float* __restrict__ bF, const float* __restrict__ bB,
    u32* __restrict__ hs2, float* __restrict__ out_tail, int* flags)
{
  extern __shared__ __align__(16) u16 Bs[];   // [NSL][2][64][8]
  __shared__ __align__(16) u32 stg[4][64];    // per-wave 256B store staging

  // one-time: clear stale lines (poison / previous replay) from L1/L2
  __builtin_amdgcn_fence(__ATOMIC_ACQUIRE, "agent");

  const int bid = blockIdx.x;
  const int dir = bid >> 7;
  const int nb  = bid & 127;
  const int n0  = nb * 32;
  const u16* __restrict__ Wc   = dir ? WcB : WcF;
  const float* __restrict__ bias = dir ? bB : bF;

  const int tid  = threadIdx.x;
  const int w    = tid >> 6, lane = tid & 63;
  const int r    = lane & 15, q = lane >> 4, rq = r >> 2;
  int* __restrict__ fl = flags + (dir * 4 + w) * DBLK;
  const u64* __restrict__ fl64 = (const u64*)fl;

  // stage B panel into LDS: chunk c -> [ks][nt][lane] 16B
  for (int c = tid; c < NSL * 128; c += 256) {
    int ks  = c >> 7;
    int rem = c & 127;
    int nt  = rem >> 6, l2 = rem & 63;
    *(short8*)&Bs[(size_t)c * 8] =
        *(const short8*)(Wc + (size_t)(n0 + nt*16 + (l2 & 15)) * KC + ks*32 + (l2 >> 4)*8);
  }
  #define BSF(ks, nt) (*(const short8*)&Bs[((size_t)(((ks)*2 + (nt))*64 + lane))*8])

  const int jbase = nb * 8;
  float bia[2][4];
  #pragma unroll
  for (int nt = 0; nt < 2; ++nt)
    #pragma unroll
    for (int g = 0; g < 4; ++g)
      bia[nt][g] = bias[g * HID + jbase + 2*rq + nt];

  float creg[2][4];
  #pragma unroll
  for (int nt = 0; nt < 2; ++nt)
    #pragma unroll
    for (int rg = 0; rg < 4; ++rg) creg[nt][rg] = 0.f;

  const int row_a = w * 16 + r;

  // prefetch x fragments for step 0
  short8 xf[8];
  {
    const int tt0 = dir ? (T_SEQ - 1) : 0;
    const u16* axr = xb + ((size_t)tt0 * BATCH + row_a) * INP;
    #pragma unroll
    for (int kx = 0; kx < 8; ++kx) xf[kx] = *(const short8*)(axr + kx*32 + q*8);
  }
  __syncthreads();   // Bs staged (only block-wide barrier)

  // x-part MFMAs of step 0 (tail-issued structure)
  f32x4 accA[2], accB[2];
  accA[0] = (f32x4)(0.f); accA[1] = (f32x4)(0.f);
  accB[0] = (f32x4)(0.f); accB[1] = (f32x4)(0.f);
  #pragma unroll
  for (int kx = 0; kx < 8; ++kx) {
    accA[0] = MFMA16(xf[kx], BSF(32 + kx, 0), accA[0]);
    accA[1] = MFMA16(xf[kx], BSF(32 + kx, 1), accA[1]);
  }

  u64 pf = 0;   // rolling flag-pair value (blocks 2*lane, 2*lane+1)

  // pipelined wait: issue next flag load BEFORE checking the current value;
  // flags are monotonic, so ready-ballots accumulate with OR.
  #define WAITG(g) \
    while (((bal >> (8*(g))) & 0xffull) != 0xffull) { \
      u64 nf = ag_ld_u64(fl64 + lane); \
      okv  = ((int)(pf & 0xffffffffu) >= s) && ((int)(pf >> 32) >= s); \
      bal |= __ballot(okv); \
      pf   = nf; \
    }
  #define LOADG(B, g) \
    B[0] = *(const short8*)(ar + (size_t)((g)*4 + 0) * 1024); \
    B[1] = *(const short8*)(ar + (size_t)((g)*4 + 1) * 1024); \
    B[2] = *(const short8*)(ar + (size_t)((g)*4 + 2) * 1024); \
    B[3] = *(const short8*)(ar + (size_t)((g)*4 + 3) * 1024);
  #define MFMAG(B, g) \
    accA[0] = MFMA16(B[0], BSF((g)*4 + 0, 0), accA[0]); \
    accA[1] = MFMA16(B[0], BSF((g)*4 + 0, 1), accA[1]); \
    accB[0] = MFMA16(B[1], BSF((g)*4 + 1, 0), accB[0]); \
    accB[1] = MFMA16(B[1], BSF((g)*4 + 1, 1), accB[1]); \
    accA[0] = MFMA16(B[2], BSF((g)*4 + 2, 0), accA[0]); \
    accA[1] = MFMA16(B[2], BSF((g)*4 + 2, 1), accA[1]); \
    accB[0] = MFMA16(B[3], BSF((g)*4 + 3, 0), accB[0]); \
    accB[1] = MFMA16(B[3], BSF((g)*4 + 3, 1), accB[1]);

  for (int s = 0; s < T_SEQ; ++s) {
    const int tt = dir ? (T_SEQ - 1 - s) : s;

    if (s > 0) {
      int okv = ((int)(pf & 0xffffffffu) >= s) && ((int)(pf >> 32) >= s);
      u64 bal = __ballot(okv);
      const int tp = dir ? tt + 1 : tt - 1;
      const u32* __restrict__ ar =
          hs2 + (((size_t)(tp * 2 + dir) * 128 + q) * 64 + row_a) * 4;
      short8 B0[4], B1[4], B2[4], B3[4];
      WAITG(0) LOADG(B0, 0)
      WAITG(1) LOADG(B1, 1)
      WAITG(2) LOADG(B2, 2)
      WAITG(3) LOADG(B3, 3)
      MFMAG(B0, 0) WAITG(4) LOADG(B0, 4)
      MFMAG(B1, 1) WAITG(5) LOADG(B1, 5)
      MFMAG(B2, 2) WAITG(6) LOADG(B2, 6)
      MFMAG(B3, 3) WAITG(7) LOADG(B3, 7)
      MFMAG(B0, 4)
      MFMAG(B1, 5)
      MFMAG(B2, 6)
      MFMAG(B3, 7)
    }

    // merge chains + cell update (DPP quad gather; gate = r&3)
    float hnv[2][4];
    #pragma unroll
    for (int nt = 0; nt < 2; ++nt) {
      #pragma unroll
      for (int rg = 0; rg < 4; ++rg) {
        float v  = accA[nt][rg] + accB[nt][rg];
        float x1 = qperm<QP_XOR1>(v);
        float x2 = qperm<QP_XOR2>(v);
        float x3 = qperm<QP_XOR2>(x1);
        float cn = sigm(x1 + bia[nt][1]) * creg[nt][rg] + sigm(v + bia[nt][0]) * tanhf_(x3 + bia[nt][3]);
        float hn = sigm(x2 + bia[nt][2]) * tanhf_(cn);
        creg[nt][rg] = cn; hnv[nt][rg] = hn;
      }
    }

    // stage packed u32s in the per-wave LDS patch (region-local layout)
    if ((r & 3) == 0) {
      #pragma unroll
      for (int rg = 0; rg < 4; ++rg) {
        u32 packed = (u32)f2bf(hnv[0][rg]) | ((u32)f2bf(hnv[1][rg]) << 16);
        stg[w][(q * 4 + rg) * 4 + rq] = packed;
      }
    }
    asm volatile("s_waitcnt lgkmcnt(0)" ::: "memory");   // within-wave LDS drain
    // coalesced sc1 stores: 16 lanes x dwordx4 = 256B contiguous (4 full lines)
    if (lane < 16) {
      u32x4 vv = *(const u32x4*)&stg[w][lane * 4];
      u32* dst = hs2 + (((size_t)(tt * 2 + dir) * 128 + nb) * 64 + w * 16 + lane) * 4;
      ag_st_u32x4(dst, vv);
    }

    if (s < T_SEQ - 1) {
      asm volatile("s_waitcnt vmcnt(0)" ::: "memory");   // h stores at IC
      if (lane == 0) ag_st_u32((u32*)(fl + nb), (u32)(s + 1));
      // issue next step's x loads + prime flag load + x-MFMAs (tail):
      // their latency overlaps the flag propagation of other blocks.
      const int tn = dir ? tt - 1 : tt + 1;
      const u16* axr = xb + ((size_t)tn * BATCH + row_a) * INP;
      #pragma unroll
      for (int kx = 0; kx < 8; ++kx) xf[kx] = *(const short8*)(axr + kx*32 + q*8);
      pf = ag_ld_u64(fl64 + lane);
      accA[0] = (f32x4)(0.f); accA[1] = (f32x4)(0.f);
      accB[0] = (f32x4)(0.f); accB[1] = (f32x4)(0.f);
      #pragma unroll
      for (int kx = 0; kx < 8; ++kx) {
        accA[0] = MFMA16(xf[kx], BSF(32 + kx, 0), accA[0]);
        accA[1] = MFMA16(xf[kx], BSF(32 + kx, 1), accA[1]);
      }
    } else {
      // final states ((hF,hB),(cF,cB)); plain stores (kernel-end flush)
      if ((r & 3) == 0) {
        #pragma unroll
        for (int nt = 0; nt < 2; ++nt)
          #pragma unroll
          for (int rg = 0; rg < 4; ++rg) {
            int row = w * 16 + q * 4 + rg;
            int j   = jbase + 2*rq + nt;
            out_tail[dir * (BATCH * HID) + (size_t)row * HID + j] = hnv[nt][rg];
            out_tail[2 * (BATCH * HID) + dir * (BATCH * HID) + (size_t)row * HID + j] = creg[nt][rg];
          }
      }
    }
  }
  #undef BSF
  #undef WAITG
  #undef LOADG
  #undef MFMAG
}

// ---------------------------------------------------------------------------
// Final FC: out[16384][1024] = H @ WfcT^T + b_fc, H read from hs2 layout.
// hs2[t][dir][nb][row][4 u32]: k = dir*1024 + nb*8 + c.
// ---------------------------------------------------------------------------
__global__ __launch_bounds__(256) void fc_kernel(
    const u32* __restrict__ hs2, const u16* __restrict__ WfcT,
    const float* __restrict__ bfc, float* __restrict__ out)
{
  const int m0 = blockIdx.x * 128, n0 = blockIdx.y * 128;
  __shared__ __align__(16) u16 As[128 * 32];
  __shared__ __align__(16) u16 Bs[128 * 32];
  const int tid = threadIdx.x;
  const int w = tid >> 6, lane = tid & 63;
  const int r = lane & 15, q = lane >> 4;
  const int wy = w >> 1, wx = w & 1;

  f32x4 acc[4][4];
  #pragma unroll
  for (int a = 0; a < 4; ++a)
    #pragma unroll
    for (int b = 0; b < 4; ++b) acc[a][b] = (f32x4)(0.f);

  const int lr = tid >> 1, lk = (tid & 1) * 16;

  for (int k0 = 0; k0 < 2048; k0 += 32) {
    __syncthreads();
    {
      int m = m0 + lr; int t = m >> 6, row = m & 63;
      int k = k0 + lk; int d = k >> 10, kk = k & 1023; int nb2 = kk >> 3;
      const u32* p = hs2 + (((size_t)(t * 2 + d) * 128 + nb2) * 64 + row) * 4;
      *(short8*)&As[lr * 32 + lk]     = *(const short8*)p;
      *(short8*)&As[lr * 32 + lk + 8] = *(const short8*)(p + 256);  // nb2+1
    }
    *(short8*)&Bs[lr * 32 + lk]     = *(const short8*)(WfcT + (size_t)(n0 + lr) * 2048 + k0 + lk);
    *(short8*)&Bs[lr * 32 + lk + 8] = *(const short8*)(WfcT + (size_t)(n0 + lr) * 2048 + k0 + lk + 8);
    __syncthreads();

    short8 af[4], bf[4];
    #pragma unroll
    for (int mt = 0; mt < 4; ++mt)
      af[mt] = *(const short8*)&As[(wy * 64 + mt * 16 + r) * 32 + q * 8];
    #pragma unroll
    for (int nt = 0; nt < 4; ++nt)
      bf[nt] = *(const short8*)&Bs[(wx * 64 + nt * 16 + r) * 32 + q * 8];
    #pragma unroll
    for (int mt = 0; mt < 4; ++mt)
      #pragma unroll
      for (int nt = 0; nt < 4; ++nt)
        acc[mt][nt] = __builtin_amdgcn_mfma_f32_16x16x32_bf16(af[mt], bf[nt], acc[mt][nt], 0, 0, 0);
  }

  #pragma unroll
  for (int mt = 0; mt < 4; ++mt)
    #pragma unroll
    for (int nt = 0; nt < 4; ++nt)
      #pragma unroll
      for (int reg = 0; reg < 4; ++reg) {
        int m = m0 + wy * 64 + mt * 16 + q * 4 + reg;
        int n = n0 + wx * 64 + nt * 16 + r;
        out[(size_t)m * OUTD + n] = acc[mt][nt][reg] + bfc[n];
      }
}

// ---------------------------------------------------------------------------
extern "C" void kernel_launch(void* const* d_in, const int* in_sizes, int n_in,
                              void* d_out, int out_size, void* d_ws, size_t ws_size,
                              hipStream_t stream)
{
  const float* x   = (const float*)d_in[0];
  const float* WxF = (const float*)d_in[1];
  const float* WhF = (const float*)d_in[2];
  const float* bF  = (const float*)d_in[3];
  const float* WxB = (const float*)d_in[4];
  const float* WhB = (const float*)d_in[5];
  const float* bB  = (const float*)d_in[6];
  const float* Wfc = (const float*)d_in[7];
  const float* bfc = (const float*)d_in[8];
  float* out = (float*)d_out;

  char* ws = (char*)d_ws;
  u16*  WcF   = (u16*)(ws + 0);          // 10485760
  u16*  WcB   = (u16*)(ws + 10485760);   // 10485760
  u16*  WfcT  = (u16*)(ws + 20971520);   // 4194304
  u16*  xb    = (u16*)(ws + 25165824);   // 8388608
  u32*  hs2   = (u32*)(ws + 34603008);   // 67108864 (t,dir,nb,row,4xu32)
  int*  flags = (int*)(ws + 101711872);  // 4KB (2 dirs x 4 waves x 128)

  (void)hipMemsetAsync(flags, 0, 4096, stream);   // barrier flags

  (void)hipFuncSetAttribute((const void*)lstm_persist,
                            hipFuncAttributeMaxDynamicSharedMemorySize, LDSB);

  build_wc <<<dim3(KC/64, HID/64, 8), 256, 0, stream>>>(WhF, WxF, WhB, WxB, WcF, WcB);
  build_wfc<<<dim3(2048/64, OUTD/64), 256, 0, stream>>>(Wfc, WfcT);
  conv_x   <<<(T_SEQ*BATCH*INP)/4/256, 256, 0, stream>>>(x, xb, T_SEQ*BATCH*INP);

  lstm_persist<<<NBLK, 256, LDSB, stream>>>(WcF, WcB, xb, bF, bB,
                                            hs2, out + 16777216, flags);

  fc_kernel<<<dim3(16384/128, OUTD/128), 256, 0, stream>>>(hs2, WfcT, bfc, out);
}

// Round 17
// 2402.323 us; speedup vs baseline: 2.1046x; 1.0465x over previous
//
#include <hip/hip_runtime.h>

using short8 = __attribute__((ext_vector_type(8))) short;
using f32x4  = __attribute__((ext_vector_type(4))) float;
using u32x4  = __attribute__((ext_vector_type(4))) unsigned int;

typedef unsigned short u16;
typedef unsigned int   u32;
typedef unsigned long long u64;

#define T_SEQ 256
#define BATCH 64
#define INP   256
#define HID   1024
#define GDIM  4096
#define KC    1280   // HID + INP
#define OUTD  1024

#define NSL   40     // K slices of 32 (32 h + 8 x)
#define NBLK  256
#define DBLK  128    // blocks per direction
#define LDSB  (NSL * 2 * 64 * 8 * 2)   // 81920 bytes dynamic LDS

#define MFMA16(a,b,c) __builtin_amdgcn_mfma_f32_16x16x32_bf16(a,b,c,0,0,0)

__device__ __forceinline__ u16 f2bf(float f){
  union { float f; u32 u; } v; v.f = f;
  u32 r = v.u + 0x7fffu + ((v.u >> 16) & 1u);
  return (u16)(r >> 16);
}
__device__ __forceinline__ float sigm(float x){ return 1.f/(1.f+__expf(-x)); }
__device__ __forceinline__ float tanhf_(float x){ return 1.f - 2.f/(__expf(2.f*x)+1.f); }

// agent-scope (device-coherent, IC-resident) ops — sc1
__device__ __forceinline__ void ag_st_u32(u32* p, u32 v){
  __hip_atomic_store(p, v, __ATOMIC_RELAXED, __HIP_MEMORY_SCOPE_AGENT);
}
__device__ __forceinline__ void ag_st_u32x4(u32* p, u32x4 v){
  asm volatile("global_store_dwordx4 %0, %1, off sc1" :: "v"(p), "v"(v) : "memory");
}
__device__ __forceinline__ u64 ag_ld_u64(const u64* p){
  return __hip_atomic_load(p, __ATOMIC_RELAXED, __HIP_MEMORY_SCOPE_AGENT);
}

// quad-perm DPP: 4 gates of one h-col live in one lane-quad
template<int CTRL>
__device__ __forceinline__ float qperm(float v){
  union { float f; int i; } u; u.f = v;
  u.i = __builtin_amdgcn_mov_dpp(u.i, CTRL, 0xf, 0xf, true);
  return u.f;
}
#define QP_XOR1 177   // quad_perm [1,0,3,2]
#define QP_XOR2 78    // quad_perm [2,3,0,1]

// ---------------------------------------------------------------------------
// Prep: combined recurrent weights, bf16, block-permuted column order.
// Block nb owns gate-cols [nb*32, nb*32+32); n = nb*32 + nt*16 + rq*4 + gate,
// h-col j = nb*8 + 2*rq + nt. Rows k<1024 -> Wh, k>=1024 -> Wx.
// ---------------------------------------------------------------------------
__global__ void build_wc(const float* __restrict__ WhF, const float* __restrict__ WxF,
                         const float* __restrict__ WhB, const float* __restrict__ WxB,
                         u16* __restrict__ WcF, u16* __restrict__ WcB)
{
  const int z = blockIdx.z; const int dir = z >> 2, gate = z & 3;
  const float* Wh = dir ? WhB : WhF;
  const float* Wx = dir ? WxB : WxF;
  u16* Wc = dir ? WcB : WcF;
  const int k0 = blockIdx.x * 64, j0 = blockIdx.y * 64;
  __shared__ float tile[64][65];
  const int t = threadIdx.x;
  #pragma unroll
  for (int i = 0; i < 16; ++i) {
    int idx = i*256 + t; int kr = idx >> 6, jc = idx & 63;
    int k = k0 + kr;
    float v = (k < HID) ? Wh[(size_t)k*GDIM + gate*HID + j0 + jc]
                        : Wx[(size_t)(k-HID)*GDIM + gate*HID + j0 + jc];
    tile[kr][jc] = v;
  }
  __syncthreads();
  #pragma unroll
  for (int i = 0; i < 16; ++i) {
    int idx = i*256 + t; int jc = idx >> 6, kr = idx & 63;
    int j  = j0 + jc;
    int nb = j >> 3, jl = j & 7;
    int nt = jl & 1, rq = jl >> 1;
    int n  = nb*32 + nt*16 + rq*4 + gate;
    Wc[(size_t)n*KC + k0 + kr] = f2bf(tile[kr][jc]);
  }
}

__global__ void build_wfc(const float* __restrict__ Wfc, u16* __restrict__ WfcT)
{
  const int k0 = blockIdx.x * 64;
  const int n0 = blockIdx.y * 64;
  __shared__ float tile[64][65];
  const int t = threadIdx.x;
  #pragma unroll
  for (int i = 0; i < 16; ++i) {
    int idx = i*256 + t; int kr = idx >> 6, nc = idx & 63;
    tile[kr][nc] = Wfc[(size_t)(k0+kr)*OUTD + n0 + nc];
  }
  __syncthreads();
  #pragma unroll
  for (int i = 0; i < 16; ++i) {
    int idx = i*256 + t; int nc = idx >> 6, kr = idx & 63;
    WfcT[(size_t)(n0+nc)*2048 + k0 + kr] = f2bf(tile[kr][nc]);
  }
}

__global__ void conv_x(const float* __restrict__ x, u16* __restrict__ xb, int n)
{
  int i = (blockIdx.x * blockDim.x + threadIdx.x) * 4;
  if (i < n) {
    float4 v = *(const float4*)(x + i);
    u32 lo = (u32)f2bf(v.x) | ((u32)f2bf(v.y) << 16);
    u32 hi = (u32)f2bf(v.z) | ((u32)f2bf(v.w) << 16);
    *(uint2*)(xb + i) = make_uint2(lo, hi);
  }
}

// ---------------------------------------------------------------------------
// Persistent bidirectional LSTM (r16 + x double-buffer in time).
// hs2[t][dir][nb][row 0..63][4 u32]: block-contiguous 1KB step regions.
// Next-step x loads are issued at ITERATION START (latency hides under the
// h phase), so the tail x-MFMAs fire instantly and the wave reaches its
// poll earlier — shortening every link of the 256-step chain.
// ---------------------------------------------------------------------------
__global__ __launch_bounds__(256, 1) void lstm_persist(
    const u16* __restrict__ WcF, const u16* __restrict__ WcB,
    const u16* __restrict__ xb,
    const float* __restrict__ bF, const float* __restrict__ bB,
    u32* __restrict__ hs2, float* __restrict__ out_tail, int* flags)
{
  extern __shared__ __align__(16) u16 Bs[];   // [NSL][2][64][8]
  __shared__ __align__(16) u32 stg[4][64];    // per-wave 256B store staging

  // one-time: clear stale lines (poison / previous replay) from L1/L2
  __builtin_amdgcn_fence(__ATOMIC_ACQUIRE, "agent");

  const int bid = blockIdx.x;
  const int dir = bid >> 7;
  const int nb  = bid & 127;
  const int n0  = nb * 32;
  const u16* __restrict__ Wc   = dir ? WcB : WcF;
  const float* __restrict__ bias = dir ? bB : bF;

  const int tid  = threadIdx.x;
  const int w    = tid >> 6, lane = tid & 63;
  const int r    = lane & 15, q = lane >> 4, rq = r >> 2;
  int* __restrict__ fl = flags + (dir * 4 + w) * DBLK;
  const u64* __restrict__ fl64 = (const u64*)fl;

  // stage B panel into LDS: chunk c -> [ks][nt][lane] 16B
  for (int c = tid; c < NSL * 128; c += 256) {
    int ks  = c >> 7;
    int rem = c & 127;
    int nt  = rem >> 6, l2 = rem & 63;
    *(short8*)&Bs[(size_t)c * 8] =
        *(const short8*)(Wc + (size_t)(n0 + nt*16 + (l2 & 15)) * KC + ks*32 + (l2 >> 4)*8);
  }
  #define BSF(ks, nt) (*(const short8*)&Bs[((size_t)(((ks)*2 + (nt))*64 + lane))*8])

  const int jbase = nb * 8;
  float bia[2][4];
  #pragma unroll
  for (int nt = 0; nt < 2; ++nt)
    #pragma unroll
    for (int g = 0; g < 4; ++g)
      bia[nt][g] = bias[g * HID + jbase + 2*rq + nt];

  float creg[2][4];
  #pragma unroll
  for (int nt = 0; nt < 2; ++nt)
    #pragma unroll
    for (int rg = 0; rg < 4; ++rg) creg[nt][rg] = 0.f;

  const int row_a = w * 16 + r;

  // prefetch x fragments for step 0
  short8 xf[8];
  {
    const int tt0 = dir ? (T_SEQ - 1) : 0;
    const u16* axr = xb + ((size_t)tt0 * BATCH + row_a) * INP;
    #pragma unroll
    for (int kx = 0; kx < 8; ++kx) xf[kx] = *(const short8*)(axr + kx*32 + q*8);
  }
  __syncthreads();   // Bs staged (only block-wide barrier)

  // x-part MFMAs of step 0
  f32x4 accA[2], accB[2];
  accA[0] = (f32x4)(0.f); accA[1] = (f32x4)(0.f);
  accB[0] = (f32x4)(0.f); accB[1] = (f32x4)(0.f);
  #pragma unroll
  for (int kx = 0; kx < 8; ++kx) {
    accA[0] = MFMA16(xf[kx], BSF(32 + kx, 0), accA[0]);
    accA[1] = MFMA16(xf[kx], BSF(32 + kx, 1), accA[1]);
  }

  u64 pf = 0;       // rolling flag-pair value (blocks 2*lane, 2*lane+1)
  short8 xn[8];     // next-step x fragments (loaded one full step ahead)

  // pipelined wait: issue next flag load BEFORE checking the current value;
  // flags are monotonic, so ready-ballots accumulate with OR.
  #define WAITG(g) \
    while (((bal >> (8*(g))) & 0xffull) != 0xffull) { \
      u64 nf = ag_ld_u64(fl64 + lane); \
      okv  = ((int)(pf & 0xffffffffu) >= s) && ((int)(pf >> 32) >= s); \
      bal |= __ballot(okv); \
      pf   = nf; \
    }
  #define LOADG(B, g) \
    B[0] = *(const short8*)(ar + (size_t)((g)*4 + 0) * 1024); \
    B[1] = *(const short8*)(ar + (size_t)((g)*4 + 1) * 1024); \
    B[2] = *(const short8*)(ar + (size_t)((g)*4 + 2) * 1024); \
    B[3] = *(const short8*)(ar + (size_t)((g)*4 + 3) * 1024);
  #define MFMAG(B, g) \
    accA[0] = MFMA16(B[0], BSF((g)*4 + 0, 0), accA[0]); \
    accA[1] = MFMA16(B[0], BSF((g)*4 + 0, 1), accA[1]); \
    accB[0] = MFMA16(B[1], BSF((g)*4 + 1, 0), accB[0]); \
    accB[1] = MFMA16(B[1], BSF((g)*4 + 1, 1), accB[1]); \
    accA[0] = MFMA16(B[2], BSF((g)*4 + 2, 0), accA[0]); \
    accA[1] = MFMA16(B[2], BSF((g)*4 + 2, 1), accA[1]); \
    accB[0] = MFMA16(B[3], BSF((g)*4 + 3, 0), accB[0]); \
    accB[1] = MFMA16(B[3], BSF((g)*4 + 3, 1), accB[1]);

  for (int s = 0; s < T_SEQ; ++s) {
    const int tt = dir ? (T_SEQ - 1 - s) : s;

    // issue NEXT step's x loads first — independent of everything; their
    // latency hides under the h phase (or the update at s=0).
    if (s < T_SEQ - 1) {
      const int tn = dir ? (T_SEQ - 2 - s) : (s + 1);
      const u16* axr = xb + ((size_t)tn * BATCH + row_a) * INP;
      #pragma unroll
      for (int kx = 0; kx < 8; ++kx) xn[kx] = *(const short8*)(axr + kx*32 + q*8);
    }

    if (s > 0) {
      int okv = ((int)(pf & 0xffffffffu) >= s) && ((int)(pf >> 32) >= s);
      u64 bal = __ballot(okv);
      const int tp = dir ? tt + 1 : tt - 1;
      const u32* __restrict__ ar =
          hs2 + (((size_t)(tp * 2 + dir) * 128 + q) * 64 + row_a) * 4;
      short8 B0[4], B1[4], B2[4], B3[4];
      WAITG(0) LOADG(B0, 0)
      WAITG(1) LOADG(B1, 1)
      WAITG(2) LOADG(B2, 2)
      WAITG(3) LOADG(B3, 3)
      MFMAG(B0, 0) WAITG(4) LOADG(B0, 4)
      MFMAG(B1, 1) WAITG(5) LOADG(B1, 5)
      MFMAG(B2, 2) WAITG(6) LOADG(B2, 6)
      MFMAG(B3, 3) WAITG(7) LOADG(B3, 7)
      MFMAG(B0, 4)
      MFMAG(B1, 5)
      MFMAG(B2, 6)
      MFMAG(B3, 7)
    }

    // merge chains + cell update (DPP quad gather; gate = r&3)
    float hnv[2][4];
    #pragma unroll
    for (int nt = 0; nt < 2; ++nt) {
      #pragma unroll
      for (int rg = 0; rg < 4; ++rg) {
        float v  = accA[nt][rg] + accB[nt][rg];
        float x1 = qperm<QP_XOR1>(v);
        float x2 = qperm<QP_XOR2>(v);
        float x3 = qperm<QP_XOR2>(x1);
        float cn = sigm(x1 + bia[nt][1]) * creg[nt][rg] + sigm(v + bia[nt][0]) * tanhf_(x3 + bia[nt][3]);
        float hn = sigm(x2 + bia[nt][2]) * tanhf_(cn);
        creg[nt][rg] = cn; hnv[nt][rg] = hn;
      }
    }

    // stage packed u32s in the per-wave LDS patch (region-local layout)
    if ((r & 3) == 0) {
      #pragma unroll
      for (int rg = 0; rg < 4; ++rg) {
        u32 packed = (u32)f2bf(hnv[0][rg]) | ((u32)f2bf(hnv[1][rg]) << 16);
        stg[w][(q * 4 + rg) * 4 + rq] = packed;
      }
    }
    asm volatile("s_waitcnt lgkmcnt(0)" ::: "memory");   // within-wave LDS drain
    // coalesced sc1 stores: 16 lanes x dwordx4 = 256B contiguous (4 full lines)
    if (lane < 16) {
      u32x4 vv = *(const u32x4*)&stg[w][lane * 4];
      u32* dst = hs2 + (((size_t)(tt * 2 + dir) * 128 + nb) * 64 + w * 16 + lane) * 4;
      ag_st_u32x4(dst, vv);
    }

    if (s < T_SEQ - 1) {
      asm volatile("s_waitcnt vmcnt(0)" ::: "memory");   // h stores at IC
      if (lane == 0) ag_st_u32((u32*)(fl + nb), (u32)(s + 1));
      pf = ag_ld_u64(fl64 + lane);     // prime next poll
      // x-MFMAs for step s+1: xn loaded a full step ago -> no load stall;
      // wave reaches its poll quickly.
      accA[0] = (f32x4)(0.f); accA[1] = (f32x4)(0.f);
      accB[0] = (f32x4)(0.f); accB[1] = (f32x4)(0.f);
      #pragma unroll
      for (int kx = 0; kx < 8; ++kx) {
        accA[0] = MFMA16(xn[kx], BSF(32 + kx, 0), accA[0]);
        accA[1] = MFMA16(xn[kx], BSF(32 + kx, 1), accA[1]);
      }
    } else {
      // final states ((hF,hB),(cF,cB)); plain stores (kernel-end flush)
      if ((r & 3) == 0) {
        #pragma unroll
        for (int nt = 0; nt < 2; ++nt)
          #pragma unroll
          for (int rg = 0; rg < 4; ++rg) {
            int row = w * 16 + q * 4 + rg;
            int j   = jbase + 2*rq + nt;
            out_tail[dir * (BATCH * HID) + (size_t)row * HID + j] = hnv[nt][rg];
            out_tail[2 * (BATCH * HID) + dir * (BATCH * HID) + (size_t)row * HID + j] = creg[nt][rg];
          }
      }
    }
  }
  #undef BSF
  #undef WAITG
  #undef LOADG
  #undef MFMAG
}

// ---------------------------------------------------------------------------
// Final FC: out[16384][1024] = H @ WfcT^T + b_fc, H read from hs2 layout.
// hs2[t][dir][nb][row][4 u32]: k = dir*1024 + nb*8 + c.
// ---------------------------------------------------------------------------
__global__ __launch_bounds__(256) void fc_kernel(
    const u32* __restrict__ hs2, const u16* __restrict__ WfcT,
    const float* __restrict__ bfc, float* __restrict__ out)
{
  const int m0 = blockIdx.x * 128, n0 = blockIdx.y * 128;
  __shared__ __align__(16) u16 As[128 * 32];
  __shared__ __align__(16) u16 Bs[128 * 32];
  const int tid = threadIdx.x;
  const int w = tid >> 6, lane = tid & 63;
  const int r = lane & 15, q = lane >> 4;
  const int wy = w >> 1, wx = w & 1;

  f32x4 acc[4][4];
  #pragma unroll
  for (int a = 0; a < 4; ++a)
    #pragma unroll
    for (int b = 0; b < 4; ++b) acc[a][b] = (f32x4)(0.f);

  const int lr = tid >> 1, lk = (tid & 1) * 16;

  for (int k0 = 0; k0 < 2048; k0 += 32) {
    __syncthreads();
    {
      int m = m0 + lr; int t = m >> 6, row = m & 63;
      int k = k0 + lk; int d = k >> 10, kk = k & 1023; int nb2 = kk >> 3;
      const u32* p = hs2 + (((size_t)(t * 2 + d) * 128 + nb2) * 64 + row) * 4;
      *(short8*)&As[lr * 32 + lk]     = *(const short8*)p;
      *(short8*)&As[lr * 32 + lk + 8] = *(const short8*)(p + 256);  // nb2+1
    }
    *(short8*)&Bs[lr * 32 + lk]     = *(const short8*)(WfcT + (size_t)(n0 + lr) * 2048 + k0 + lk);
    *(short8*)&Bs[lr * 32 + lk + 8] = *(const short8*)(WfcT + (size_t)(n0 + lr) * 2048 + k0 + lk + 8);
    __syncthreads();

    short8 af[4], bf[4];
    #pragma unroll
    for (int mt = 0; mt < 4; ++mt)
      af[mt] = *(const short8*)&As[(wy * 64 + mt * 16 + r) * 32 + q * 8];
    #pragma unroll
    for (int nt = 0; nt < 4; ++nt)
      bf[nt] = *(const short8*)&Bs[(wx * 64 + nt * 16 + r) * 32 + q * 8];
    #pragma unroll
    for (int mt = 0; mt < 4; ++mt)
      #pragma unroll
      for (int nt = 0; nt < 4; ++nt)
        acc[mt][nt] = __builtin_amdgcn_mfma_f32_16x16x32_bf16(af[mt], bf[nt], acc[mt][nt], 0, 0, 0);
  }

  #pragma unroll
  for (int mt = 0; mt < 4; ++mt)
    #pragma unroll
    for (int nt = 0; nt < 4; ++nt)
      #pragma unroll
      for (int reg = 0; reg < 4; ++reg) {
        int m = m0 + wy * 64 + mt * 16 + q * 4 + reg;
        int n = n0 + wx * 64 + nt * 16 + r;
        out[(size_t)m * OUTD + n] = acc[mt][nt][reg] + bfc[n];
      }
}

// ---------------------------------------------------------------------------
extern "C" void kernel_launch(void* const* d_in, const int* in_sizes, int n_in,
                              void* d_out, int out_size, void* d_ws, size_t ws_size,
                              hipStream_t stream)
{
  const float* x   = (const float*)d_in[0];
  const float* WxF = (const float*)d_in[1];
  const float* WhF = (const float*)d_in[2];
  const float* bF  = (const float*)d_in[3];
  const float* WxB = (const float*)d_in[4];
  const float* WhB = (const float*)d_in[5];
  const float* bB  = (const float*)d_in[6];
  const float* Wfc = (const float*)d_in[7];
  const float* bfc = (const float*)d_in[8];
  float* out = (float*)d_out;

  char* ws = (char*)d_ws;
  u16*  WcF   = (u16*)(ws + 0);          // 10485760
  u16*  WcB   = (u16*)(ws + 10485760);   // 10485760
  u16*  WfcT  = (u16*)(ws + 20971520);   // 4194304
  u16*  xb    = (u16*)(ws + 25165824);   // 8388608
  u32*  hs2   = (u32*)(ws + 34603008);   // 67108864 (t,dir,nb,row,4xu32)
  int*  flags = (int*)(ws + 101711872);  // 4KB (2 dirs x 4 waves x 128)

  (void)hipMemsetAsync(flags, 0, 4096, stream);   // barrier flags

  (void)hipFuncSetAttribute((const void*)lstm_persist,
                            hipFuncAttributeMaxDynamicSharedMemorySize, LDSB);

  build_wc <<<dim3(KC/64, HID/64, 8), 256, 0, stream>>>(WhF, WxF, WhB, WxB, WcF, WcB);
  build_wfc<<<dim3(2048/64, OUTD/64), 256, 0, stream>>>(Wfc, WfcT);
  conv_x   <<<(T_SEQ*BATCH*INP)/4/256, 256, 0, stream>>>(x, xb, T_SEQ*BATCH*INP);

  lstm_persist<<<NBLK, 256, LDSB, stream>>>(WcF, WcB, xb, bF, bB,
                                            hs2, out + 16777216, flags);

  fc_kernel<<<dim3(16384/128, OUTD/128), 256, 0, stream>>>(hs2, WfcT, bfc, out);
}